// Round 12
// baseline (251.879 us; speedup 1.0000x reference)
//
#include <hip/hip_runtime.h>
#include <hip/hip_bf16.h>
#include <stdint.h>

#define NNODES 100000
#define NEDGES 1000000
#define NRELS 16
#define EPB 4096
#define NB ((NEDGES + EPB - 1) / EPB)   /* 245 */
#define PADCAP (NEDGES + NRELS * 64)    /* 1001024 */
#define MAXTILES (PADCAP / 64)          /* 15641 */
#define NDN NNODES
#define BKT 256
#define NBKT ((NDN + BKT - 1) / BKT)     /* 391 dst buckets */
#define NSB 391                          /* src buckets */
#define NCB (NRELS * NSB)                /* 6256 composite (rel,srcbkt) buckets */

#define FEAT_BLKS 6250
#define W_BLKS 256
#define SETUP_BLKS (FEAT_BLKS + W_BLKS + NB)
#define CB_BLKS ((NCB + 15) / 16)        /* 391 */
#define DST_BLKS ((NBKT + 15) / 16)      /* 25 */

// ws layout (bytes):
//   featB    @ 0          : ushort[NNODES*64]   -> 12,800,000
//   Wt       @ 12800000   : ushort[16*64*64]    -> 12,931,072
//   hist_cb  @ 12931072   : int[NB*NCB]         -> 19,061,952
//   bbase_cb @ 19061952   : int[NB*NCB]         -> 25,192,832
//   cbstart  @ 25192832   : int[NCB]            -> 25,217,856
//   Pve      @ 25217856   : int[33]             -> 25,218,112 (reserve 256)
//   hist391  @ 25218112   : int[NB*NBKT]        -> 25,601,344 (reserve 383,232)
//   bbase391 @ 25601344   : int[NB*NBKT]        -> 25,984,576
//   bstart   @ 25984576   : int[NBKT+1]         -> 25,986,624 (reserve 2,048)
//   dnode    @ 25986624   : ushort[NEDGES]      -> 27,986,624
//   dnstart  @ 27986624   : int[NBKT*256+1]     -> 28,387,072 (reserve 400,448)
//   keyE     @ 28387072   : int[NEDGES]         -> 32,387,072  relpos (dst-bucket order)
//   keyS     @ 32387072   : int[NEDGES]         -> 36,387,072  relpos (dst-sorted)
//   srcS     @ 36387072   : int[PADCAP]         -> 40,391,168  src ((rel,srcbkt) order)
//   msgE     @ 40391168   : ushort[PADCAP*64]   -> 168,522,240
#define WS_NEED 168522240ull

using short8  = __attribute__((ext_vector_type(8))) short;
using floatx4 = __attribute__((ext_vector_type(4))) float;
using uintx4  = __attribute__((ext_vector_type(4))) unsigned int;

__device__ __forceinline__ unsigned short f2bf(float f) {
    union { float f; uint32_t u; } v; v.f = f;
    uint32_t u = v.u;
    return (unsigned short)((u + 0x7FFFu + ((u >> 16) & 1u)) >> 16);
}
__device__ __forceinline__ float bf2f(uint32_t u16) {
    union { uint32_t u; float f; } v; v.u = u16 << 16;
    return v.f;
}
__device__ __forceinline__ uint32_t pk2(float a, float b) {
    __hip_bfloat162 h = __float22bfloat162_rn(make_float2(a, b));
    union { __hip_bfloat162 h; uint32_t u; } v; v.h = h;
    return v.u;
}

// fused setup: feat->bf16, W->bf16 transposed, per-block (rel,srcbkt) hist + dst hist.
// LDS atomics only.
__global__ void k_setup(const float* __restrict__ feat, const float* __restrict__ W,
                        const int* __restrict__ et, const int* __restrict__ src,
                        const int* __restrict__ dst,
                        unsigned short* __restrict__ featB, unsigned short* __restrict__ Wt,
                        int* __restrict__ hist_cb, int* __restrict__ hist391) {
    __shared__ int cnt_cb[NCB];
    __shared__ int cnt391[NBKT];
    const int b = blockIdx.x;
    if (b < FEAT_BLKS) {
        int i = (b * 256 + threadIdx.x) * 4;
        const float4 f = *(const float4*)(feat + i);
        ushort4 o;
        o.x = f2bf(f.x); o.y = f2bf(f.y); o.z = f2bf(f.z); o.w = f2bf(f.w);
        *(ushort4*)(featB + i) = o;
    } else if (b < FEAT_BLKS + W_BLKS) {
        int t = (b - FEAT_BLKS) * 256 + threadIdx.x;   // 65536 total
        int r = t >> 12, n = (t >> 6) & 63, k = t & 63;
        Wt[t] = f2bf(W[(r << 12) + (k << 6) + n]);     // Wt[r][n][k] = W[r][k][n]
    } else {
        const int bb = b - (FEAT_BLKS + W_BLKS);
        for (int t = threadIdx.x; t < NCB; t += 256) cnt_cb[t] = 0;
        for (int t = threadIdx.x; t < NBKT; t += 256) cnt391[t] = 0;
        __syncthreads();
        int start = bb * EPB;
        int end = min(NEDGES, start + EPB);
        for (int i = start + threadIdx.x; i < end; i += 256) {
            atomicAdd(&cnt_cb[et[i] * NSB + (src[i] >> 8)], 1);
            atomicAdd(&cnt391[dst[i] >> 8], 1);
        }
        __syncthreads();
        for (int t = threadIdx.x; t < NCB; t += 256)
            hist_cb[bb * NCB + t] = cnt_cb[t];
        for (int t = threadIdx.x; t < NBKT; t += 256)
            hist391[bb * NBKT + t] = cnt391[t];
    }
}

// scan A: wave-per-bucket exclusive scan over NB blocks; totals out.
// blocks [0,CB_BLKS): composite buckets -> cbstart; rest: dst buckets -> bstart.
__global__ void __launch_bounds__(1024)
k_scanA(const int* __restrict__ hist_cb, int* __restrict__ bbase_cb,
        int* __restrict__ cbstart,
        const int* __restrict__ hist391, int* __restrict__ bbase391,
        int* __restrict__ bstart) {
    int w = threadIdx.x >> 6, lane = threadIdx.x & 63;
    if (blockIdx.x < CB_BLKS) {
        int b = blockIdx.x * 16 + w;           // < 6256 exactly
        int carry = 0;
        for (int c = 0; c < NB; c += 64) {
            int idx = c + lane;
            int v = (idx < NB) ? hist_cb[idx * NCB + b] : 0;
            int x = v;
            #pragma unroll
            for (int off = 1; off < 64; off <<= 1) {
                int y = __shfl_up(x, off);
                if (lane >= off) x += y;
            }
            if (idx < NB) bbase_cb[idx * NCB + b] = carry + x - v;
            carry += __shfl(x, 63);
        }
        if (lane == 0) cbstart[b] = carry;     // totals; scanned in k_scanB
    } else {
        int b = (blockIdx.x - CB_BLKS) * 16 + w;
        if (b >= NBKT) return;
        int carry = 0;
        for (int c = 0; c < NB; c += 64) {
            int idx = c + lane;
            int v = (idx < NB) ? hist391[idx * NBKT + b] : 0;
            int x = v;
            #pragma unroll
            for (int off = 1; off < 64; off <<= 1) {
                int y = __shfl_up(x, off);
                if (lane >= off) x += y;
            }
            if (idx < NB) bbase391[idx * NBKT + b] = carry + x - v;
            carry += __shfl(x, 63);
        }
        if (lane == 0) bstart[b] = carry;      // totals; scanned in k_scanB
    }
}

// scan B (1 block, 1024 thr): phase 1 = within-relation scan of composite totals
// + 64-padded relation bases (Pve); phase 2 = dst bstart exclusive scan.
__global__ void __launch_bounds__(1024)
k_scanB(int* __restrict__ cbstart, int* __restrict__ Pve, int* __restrict__ bstart) {
    __shared__ int s_cnt[16];
    __shared__ int s_P[17];
    __shared__ int wtot[16];
    int w = threadIdx.x >> 6, lane = threadIdx.x & 63;
    // phase 1: wave w = relation w scans its NSB bucket totals
    int carry = 0;
    for (int c = 0; c < NSB; c += 64) {
        int idx = c + lane;
        int v = (idx < NSB) ? cbstart[w * NSB + idx] : 0;
        int x = v;
        #pragma unroll
        for (int off = 1; off < 64; off <<= 1) {
            int y = __shfl_up(x, off);
            if (lane >= off) x += y;
        }
        if (idx < NSB) cbstart[w * NSB + idx] = carry + x - v;
        carry += __shfl(x, 63);
    }
    if (lane == 0) s_cnt[w] = carry;
    __syncthreads();
    if (threadIdx.x == 0) {
        int p = 0;
        for (int r = 0; r < 16; ++r) {
            s_P[r] = p;
            Pve[r] = p;
            Pve[17 + r] = p + s_cnt[r];
            p += (s_cnt[r] + 63) & ~63;     // pad relation to 64
        }
        Pve[16] = p;
    }
    __syncthreads();
    int pw = s_P[w];
    for (int idx = lane; idx < NSB; idx += 64)
        cbstart[w * NSB + idx] += pw;
    __syncthreads();
    // phase 2: dst bucket starts
    int t = threadIdx.x;
    int v = (t < NBKT) ? bstart[t] : 0;
    int x = v;
    #pragma unroll
    for (int off = 1; off < 64; off <<= 1) {
        int y = __shfl_up(x, off);
        if (lane >= off) x += y;
    }
    if (lane == 63) wtot[w] = x;
    __syncthreads();
    int woff = 0;
    for (int i = 0; i < w; ++i) woff += wtot[i];
    if (t < NBKT) bstart[t] = woff + x - v;
    if (t == 1023) {
        int total = 0;
        for (int i = 0; i < 16; ++i) total += wtot[i];
        bstart[NBKT] = total;
    }
}

// scatter: srcS[pos] = src at (rel,srcbkt)-sorted pos; keyE[bp] = pos; dnode = dst&255.
// LDS atomics only.
__global__ void __launch_bounds__(256)
k_scatter(const int* __restrict__ et, const int* __restrict__ src,
          const int* __restrict__ dst,
          const int* __restrict__ bbase_cb, const int* __restrict__ cbstart,
          const int* __restrict__ bbase391, const int* __restrict__ bstart,
          int* __restrict__ srcS, int* __restrict__ keyE,
          unsigned short* __restrict__ dnode) {
    __shared__ int base_cb[NCB];     // 25,024 B
    __shared__ int base391[NBKT];    //  1,564 B
    for (int t = threadIdx.x; t < NCB; t += 256)
        base_cb[t] = bbase_cb[blockIdx.x * NCB + t] + cbstart[t];
    for (int t = threadIdx.x; t < NBKT; t += 256)
        base391[t] = bbase391[blockIdx.x * NBKT + t] + bstart[t];
    __syncthreads();
    int start = blockIdx.x * EPB;
    int end = min(NEDGES, start + EPB);
    for (int i = start + threadIdx.x; i < end; i += 256) {
        int s = src[i];
        int pos = atomicAdd(&base_cb[et[i] * NSB + (s >> 8)], 1);
        srcS[pos] = s;
        int d = dst[i];
        int bp = atomicAdd(&base391[d >> 8], 1);
        keyE[bp] = pos;
        dnode[bp] = (unsigned short)(d & 255);
    }
}

// refine dst-bucket order into full dst sort; keyS[dstpos] = relpos; dnstart per node.
__global__ void __launch_bounds__(256)
k_bsort(const unsigned short* __restrict__ dnode, const int* __restrict__ keyE,
        const int* __restrict__ bstart,
        int* __restrict__ keyS, int* __restrict__ dnstart) {
    __shared__ int cnt[256];
    __shared__ int nodebase[256];
    __shared__ int wtot[4];
    const int b = blockIdx.x;
    const int start = bstart[b], end = bstart[b + 1];
    const int t = threadIdx.x;
    cnt[t] = 0;
    __syncthreads();
    for (int e = start + t; e < end; e += 256)
        atomicAdd(&cnt[dnode[e]], 1);
    __syncthreads();
    int v = cnt[t];
    int lane = t & 63, w = t >> 6;
    int x = v;
    #pragma unroll
    for (int off = 1; off < 64; off <<= 1) {
        int y = __shfl_up(x, off);
        if (lane >= off) x += y;
    }
    if (lane == 63) wtot[w] = x;
    __syncthreads();
    int woff = 0;
    for (int i = 0; i < w; ++i) woff += wtot[i];
    nodebase[t] = woff + x - v;          // exclusive scan
    cnt[t] = 0;
    __syncthreads();
    dnstart[b * 256 + t] = start + nodebase[t];
    if (b == NBKT - 1 && t == 255) dnstart[NBKT * 256] = end;
    for (int e = start + t; e < end; e += 256) {
        int node = dnode[e];
        int rk = atomicAdd(&cnt[node], 1);
        keyS[start + nodebase[node] + rk] = keyE[e];
    }
}

// Phase A: per 64-edge tile (single relation), GEMM -> msgE row at OWN position.
// srcS is (rel,srcbkt)-sorted: featB gather has L2 locality. Sequential plain stores.
__global__ void __launch_bounds__(256)
k_computeA(const unsigned short* __restrict__ featB,
           const unsigned short* __restrict__ Wt,
           const int* __restrict__ srcS, const int* __restrict__ Pve,
           unsigned short* __restrict__ msgE) {
    __shared__ float lds[4][16 * 68];   // per-wave 16x64 transpose, stride 68
    const int w = threadIdx.x >> 6;
    const int t = blockIdx.x * 4 + w;
    const int base = t * 64;
    const int total = Pve[16];
    if (base >= total) return;
    int r = 0;
    while (base >= Pve[r + 1]) ++r;
    const int validEnd = Pve[17 + r];
    const int lane = threadIdx.x & 63;
    const int quad = lane >> 4;
    const int l16 = lane & 15;

    const unsigned short* wr = Wt + (r << 12);
    short8 bfr[4][2];
    #pragma unroll
    for (int tn = 0; tn < 4; ++tn)
        #pragma unroll
        for (int ks = 0; ks < 2; ++ks)
            bfr[tn][ks] = *(const short8*)(wr + ((tn * 16 + l16) << 6) + ks * 32 + quad * 8);

    const int rr = lane >> 2, seg = lane & 3;
    #pragma unroll
    for (int tm = 0; tm < 4; ++tm) {
        int row = base + tm * 16 + l16;
        int s = (row < validEnd) ? srcS[row] : 0;
        const unsigned short* fp = featB + (s << 6) + quad * 8;
        short8 a0 = *(const short8*)(fp);
        short8 a1 = *(const short8*)(fp + 32);
        #pragma unroll
        for (int tn = 0; tn < 4; ++tn) {
            floatx4 c = {0.f, 0.f, 0.f, 0.f};
            c = __builtin_amdgcn_mfma_f32_16x16x32_bf16(a0, bfr[tn][0], c, 0, 0, 0);
            c = __builtin_amdgcn_mfma_f32_16x16x32_bf16(a1, bfr[tn][1], c, 0, 0, 0);
            #pragma unroll
            for (int j = 0; j < 4; ++j)
                lds[w][(quad * 4 + j) * 68 + tn * 16 + l16] = c[j];
        }
        // lane l writes output row (l>>2) at its OWN global position — sequential
        int grow = base + tm * 16 + rr;
        const float* lp = &lds[w][rr * 68 + seg * 16];
        uintx4 o0, o1;
        o0.x = pk2(lp[0],  lp[1]);  o0.y = pk2(lp[2],  lp[3]);
        o0.z = pk2(lp[4],  lp[5]);  o0.w = pk2(lp[6],  lp[7]);
        o1.x = pk2(lp[8],  lp[9]);  o1.y = pk2(lp[10], lp[11]);
        o1.z = pk2(lp[12], lp[13]); o1.w = pk2(lp[14], lp[15]);
        uintx4* op = (uintx4*)(msgE + (size_t)grow * 64 + seg * 16);
        op[0] = o0;
        op[1] = o1;
    }
}

// Phase B: one wave per dst node; rows gathered via keyS (random 128B, cache-served).
__global__ void __launch_bounds__(256)
k_reduce(const unsigned short* __restrict__ msgE, const int* __restrict__ keyS,
         const int* __restrict__ dnstart, float* __restrict__ out) {
    int n = blockIdx.x * 4 + (threadIdx.x >> 6);
    if (n >= NDN) return;
    int lane = threadIdx.x & 63;
    int start = dnstart[n];
    int end = dnstart[n + 1];
    int c8 = (lane & 7) * 8;   // ushort col offset
    float a0 = 0.f, a1 = 0.f, a2 = 0.f, a3 = 0.f;
    float a4 = 0.f, a5 = 0.f, a6 = 0.f, a7 = 0.f;
    for (int row = start + (lane >> 3); row < end; row += 8) {
        int rp = keyS[row];
        uintx4 v = *(const uintx4*)(msgE + (size_t)rp * 64 + c8);
        a0 += bf2f(v.x & 0xffffu); a1 += bf2f(v.x >> 16);
        a2 += bf2f(v.y & 0xffffu); a3 += bf2f(v.y >> 16);
        a4 += bf2f(v.z & 0xffffu); a5 += bf2f(v.z >> 16);
        a6 += bf2f(v.w & 0xffffu); a7 += bf2f(v.w >> 16);
    }
    #pragma unroll
    for (int m = 8; m <= 32; m <<= 1) {
        a0 += __shfl_xor(a0, m); a1 += __shfl_xor(a1, m);
        a2 += __shfl_xor(a2, m); a3 += __shfl_xor(a3, m);
        a4 += __shfl_xor(a4, m); a5 += __shfl_xor(a5, m);
        a6 += __shfl_xor(a6, m); a7 += __shfl_xor(a7, m);
    }
    if (lane < 8) {
        float* op = out + (size_t)n * 64 + lane * 8;
        *(float4*)(op)     = make_float4(a0, a1, a2, a3);
        *(float4*)(op + 4) = make_float4(a4, a5, a6, a7);
    }
}

// Fallback (ws too small): correctness-only per-edge kernel on raw fp32 inputs.
__global__ void __launch_bounds__(256)
k_fb(const float* __restrict__ feat, const float* __restrict__ W,
     const int* __restrict__ src, const int* __restrict__ dst,
     const int* __restrict__ et, float* __restrict__ out) {
    int e = blockIdx.x * 4 + (threadIdx.x >> 6);
    if (e >= NEDGES) return;
    int c = threadIdx.x & 63;
    int s = src[e], d = dst[e], r = et[e];
    const float* fr = feat + (size_t)s * 64;
    const float* wr = W + ((size_t)r << 12);
    float acc = 0.f;
    for (int k = 0; k < 64; ++k) acc += fr[k] * wr[k * 64 + c];
    atomicAdd(out + (size_t)d * 64 + c, acc);
}

extern "C" void kernel_launch(void* const* d_in, const int* in_sizes, int n_in,
                              void* d_out, int out_size, void* d_ws, size_t ws_size,
                              hipStream_t stream) {
    const float* feat = (const float*)d_in[0];
    const float* W    = (const float*)d_in[1];
    const int* src    = (const int*)d_in[2];
    const int* dst    = (const int*)d_in[3];
    const int* et     = (const int*)d_in[4];
    float* out = (float*)d_out;
    char* ws = (char*)d_ws;

    unsigned short* featB = (unsigned short*)(ws);
    unsigned short* Wt    = (unsigned short*)(ws + 12800000);
    int* hist_cb  = (int*)(ws + 12931072);
    int* bbase_cb = (int*)(ws + 19061952);
    int* cbstart  = (int*)(ws + 25192832);
    int* Pve      = (int*)(ws + 25217856);
    int* hist391  = (int*)(ws + 25218112);
    int* bbase391 = (int*)(ws + 25601344);
    int* bstart   = (int*)(ws + 25984576);
    unsigned short* dnode = (unsigned short*)(ws + 25986624);
    int* dnstart  = (int*)(ws + 27986624);
    int* keyE     = (int*)(ws + 28387072);
    int* keyS     = (int*)(ws + 32387072);
    int* srcS     = (int*)(ws + 36387072);
    unsigned short* msgE = (unsigned short*)(ws + 40391168);

    if (ws_size >= WS_NEED) {
        k_setup<<<SETUP_BLKS, 256, 0, stream>>>(feat, W, et, src, dst, featB, Wt,
                                                hist_cb, hist391);
        k_scanA<<<CB_BLKS + DST_BLKS, 1024, 0, stream>>>(hist_cb, bbase_cb, cbstart,
                                                         hist391, bbase391, bstart);
        k_scanB<<<1, 1024, 0, stream>>>(cbstart, Pve, bstart);
        k_scatter<<<NB, 256, 0, stream>>>(et, src, dst, bbase_cb, cbstart,
                                          bbase391, bstart, srcS, keyE, dnode);
        k_bsort<<<NBKT, 256, 0, stream>>>(dnode, keyE, bstart, keyS, dnstart);
        k_computeA<<<(MAXTILES + 3) / 4, 256, 0, stream>>>(featB, Wt, srcS, Pve, msgE);
        k_reduce<<<(NDN + 3) / 4, 256, 0, stream>>>(msgE, keyS, dnstart, out);
    } else {
        hipMemsetAsync(d_out, 0, (size_t)out_size * sizeof(float), stream);
        k_fb<<<(NEDGES + 3) / 4, 256, 0, stream>>>(feat, W, src, dst, et, out);
    }
}